// Round 4
// baseline (3112.030 us; speedup 1.0000x reference)
//
#include <hip/hip_runtime.h>
#include <hip/hip_fp16.h>

typedef unsigned int u32;
typedef unsigned short u16;
typedef u32 __attribute__((may_alias)) u32a;
typedef u16 __attribute__((may_alias)) u16a;
typedef uint4 __attribute__((may_alias)) uint4a;
typedef float __attribute__((may_alias)) f32a;

#define BATCH 16
#define CIN   512
#define NPIX  4096
#define DD    64
#define VV    256
#define MM    1024

__device__ __forceinline__ float b2f(u16 u) {
  union { u32 i; float f; } v; v.i = ((u32)u) << 16; return v.f;
}
__device__ __forceinline__ u16 f2b(float f) {
  union { float f; u32 i; } v; v.f = f;
  u32 u = v.i;
  u32 r = (u + 0x7fffu + ((u >> 16) & 1u)) >> 16;
  return (u16)r;
}
__device__ __forceinline__ u16 f2h(float f) { return __half_as_ushort(__float2half(f)); }
__device__ __forceinline__ float h2f(u16 u) { return __half2float(__ushort_as_half(u)); }

// packed bf16x2 dot product, f32 accumulate — plain-fma version
__device__ __forceinline__ float dot2(u32 a, u32 b, float c) {
  union { u32 i; float f; } a0, a1, b0, b1;
  a0.i = a << 16; a1.i = a & 0xffff0000u;
  b0.i = b << 16; b1.i = b & 0xffff0000u;
  return fmaf(a1.f, b1.f, fmaf(a0.f, b0.f, c));
}

// ---------------------------------------------------------------------------
// K0a: input-dtype detection. Even u16 halves of fp32 data are mantissa bits
// (uniform random exponent when viewed as bf16); true-bf16 N(0,1) data sits
// in [1e-6, 100].  meta[0] = 1 (inputs fp32) or 0 (inputs bf16).
// ---------------------------------------------------------------------------
__global__ __launch_bounds__(256) void k_detect(const void* __restrict__ x,
                                                u32* __restrict__ meta) {
  __shared__ int bad[256];
  const int t = threadIdx.x;
  float f = b2f(((const u16a*)x)[2 * t]);
  float a = fabsf(f);
  bad[t] = (a >= 1e-6f && a <= 100.f) ? 0 : 1;  // NaN -> bad (compares false)
  __syncthreads();
  if (t == 0) {
    int s = 0;
#pragma unroll 16
    for (int i = 0; i < 256; ++i) s += bad[i];
    meta[0] = (s > 64) ? 1u : 0u;
  }
}

// ---------------------------------------------------------------------------
// K0b: weights (+gamma) -> bf16 copy in ws.  wbf layout: wt@0, wp@32768,
// wg@65536, wo@196608 (u16 elements).  grid = 1280 x 256.
// ---------------------------------------------------------------------------
__global__ __launch_bounds__(256) void k_cvt(
    const void* __restrict__ wt, const void* __restrict__ wp,
    const void* __restrict__ wg, const void* __restrict__ wo,
    const void* __restrict__ gm, const u32* __restrict__ meta,
    u16* __restrict__ wbf, float* __restrict__ gout) {
  const int flag = (int)meta[0];
  const int i = blockIdx.x * 256 + threadIdx.x;
  const void* src; int j;
  if (i < 32768)       { src = wt; j = i; }
  else if (i < 65536)  { src = wp; j = i - 32768; }
  else if (i < 196608) { src = wg; j = i - 65536; }
  else                 { src = wo; j = i - 196608; }
  wbf[i] = flag ? f2b(((const f32a*)src)[j]) : ((const u16a*)src)[j];
  if (i == 0)
    gout[0] = flag ? ((const f32a*)gm)[0] : b2f(((const u16a*)gm)[0]);
}

// ---------------------------------------------------------------------------
// K1: theta/phi/g projections (1x1 convs) + fused 2x2 maxpool for phi,g.
// grid = 16 b * 32 yp * 4 og.  theta -> [b][d][n]; phi -> [b][m][d]; g -> [b][v][m]
// ---------------------------------------------------------------------------
__global__ __launch_bounds__(256) void k_proj(
    const void* __restrict__ x, const u16* __restrict__ wt,
    const u16* __restrict__ wp, const u16* __restrict__ wg,
    const u32* __restrict__ meta,
    u16* __restrict__ theta, u16* __restrict__ phi_t, u16* __restrict__ g)
{
  __shared__ __align__(16) u16 xs[128][134];
  const int tid  = threadIdx.x;
  const int lane = tid & 63;
  const int wv   = tid >> 6;
  const int blk  = blockIdx.x;
  const int b  = blk >> 7;
  const int yp = (blk >> 2) & 31;
  const int og = blk & 3;
  const int n0 = yp * 128;
  const int rbase = og * 96 + wv * 24;
  const int flag = (int)meta[0];

  float acc[24][2];
#pragma unroll
  for (int i = 0; i < 24; ++i) { acc[i][0] = 0.f; acc[i][1] = 0.f; }

  for (int cc = 0; cc < 4; ++cc) {
    const int c0 = cc * 128;
    __syncthreads();
    if (flag) {
#pragma unroll 8
      for (int it = 0; it < 64; ++it) {
        int idx = tid + it * 256;
        int cl = idx >> 7, px = idx & 127;
        xs[px][cl] = f2b(((const f32a*)x)[((size_t)(b * CIN + c0 + cl)) * NPIX + (n0 + px)]);
      }
    } else {
#pragma unroll 8
      for (int it = 0; it < 64; ++it) {
        int idx = tid + it * 256;
        int cl = idx >> 7, px = idx & 127;
        xs[px][cl] = ((const u16a*)x)[((size_t)(b * CIN + c0 + cl)) * NPIX + (n0 + px)];
      }
    }
    __syncthreads();
#pragma unroll
    for (int grp = 0; grp < 6; ++grp) {
      const int r0g = rbase + grp * 4;
      const u16* wr0; const u16* wr1; const u16* wr2; const u16* wr3;
      {
        int r = r0g;
        wr0 = (r < 64 ? wt + (size_t)r * CIN : (r < 128 ? wp + (size_t)(r-64) * CIN : wg + (size_t)(r-128) * CIN)) + c0;
        r = r0g + 1;
        wr1 = (r < 64 ? wt + (size_t)r * CIN : (r < 128 ? wp + (size_t)(r-64) * CIN : wg + (size_t)(r-128) * CIN)) + c0;
        r = r0g + 2;
        wr2 = (r < 64 ? wt + (size_t)r * CIN : (r < 128 ? wp + (size_t)(r-64) * CIN : wg + (size_t)(r-128) * CIN)) + c0;
        r = r0g + 3;
        wr3 = (r < 64 ? wt + (size_t)r * CIN : (r < 128 ? wp + (size_t)(r-64) * CIN : wg + (size_t)(r-128) * CIN)) + c0;
      }
#pragma unroll 2
      for (int cl = 0; cl < 128; cl += 8) {
        u32 xa0 = *(const u32a*)&xs[lane][cl];
        u32 xa1 = *(const u32a*)&xs[lane][cl + 2];
        u32 xa2 = *(const u32a*)&xs[lane][cl + 4];
        u32 xa3 = *(const u32a*)&xs[lane][cl + 6];
        u32 xb0 = *(const u32a*)&xs[lane + 64][cl];
        u32 xb1 = *(const u32a*)&xs[lane + 64][cl + 2];
        u32 xb2 = *(const u32a*)&xs[lane + 64][cl + 4];
        u32 xb3 = *(const u32a*)&xs[lane + 64][cl + 6];
        {
          uint4 w4 = *(const uint4a*)(wr0 + cl);
          acc[grp*4+0][0] = dot2(xa0, w4.x, acc[grp*4+0][0]);
          acc[grp*4+0][0] = dot2(xa1, w4.y, acc[grp*4+0][0]);
          acc[grp*4+0][0] = dot2(xa2, w4.z, acc[grp*4+0][0]);
          acc[grp*4+0][0] = dot2(xa3, w4.w, acc[grp*4+0][0]);
          acc[grp*4+0][1] = dot2(xb0, w4.x, acc[grp*4+0][1]);
          acc[grp*4+0][1] = dot2(xb1, w4.y, acc[grp*4+0][1]);
          acc[grp*4+0][1] = dot2(xb2, w4.z, acc[grp*4+0][1]);
          acc[grp*4+0][1] = dot2(xb3, w4.w, acc[grp*4+0][1]);
        }
        {
          uint4 w4 = *(const uint4a*)(wr1 + cl);
          acc[grp*4+1][0] = dot2(xa0, w4.x, acc[grp*4+1][0]);
          acc[grp*4+1][0] = dot2(xa1, w4.y, acc[grp*4+1][0]);
          acc[grp*4+1][0] = dot2(xa2, w4.z, acc[grp*4+1][0]);
          acc[grp*4+1][0] = dot2(xa3, w4.w, acc[grp*4+1][0]);
          acc[grp*4+1][1] = dot2(xb0, w4.x, acc[grp*4+1][1]);
          acc[grp*4+1][1] = dot2(xb1, w4.y, acc[grp*4+1][1]);
          acc[grp*4+1][1] = dot2(xb2, w4.z, acc[grp*4+1][1]);
          acc[grp*4+1][1] = dot2(xb3, w4.w, acc[grp*4+1][1]);
        }
        {
          uint4 w4 = *(const uint4a*)(wr2 + cl);
          acc[grp*4+2][0] = dot2(xa0, w4.x, acc[grp*4+2][0]);
          acc[grp*4+2][0] = dot2(xa1, w4.y, acc[grp*4+2][0]);
          acc[grp*4+2][0] = dot2(xa2, w4.z, acc[grp*4+2][0]);
          acc[grp*4+2][0] = dot2(xa3, w4.w, acc[grp*4+2][0]);
          acc[grp*4+2][1] = dot2(xb0, w4.x, acc[grp*4+2][1]);
          acc[grp*4+2][1] = dot2(xb1, w4.y, acc[grp*4+2][1]);
          acc[grp*4+2][1] = dot2(xb2, w4.z, acc[grp*4+2][1]);
          acc[grp*4+2][1] = dot2(xb3, w4.w, acc[grp*4+2][1]);
        }
        {
          uint4 w4 = *(const uint4a*)(wr3 + cl);
          acc[grp*4+3][0] = dot2(xa0, w4.x, acc[grp*4+3][0]);
          acc[grp*4+3][0] = dot2(xa1, w4.y, acc[grp*4+3][0]);
          acc[grp*4+3][0] = dot2(xa2, w4.z, acc[grp*4+3][0]);
          acc[grp*4+3][0] = dot2(xa3, w4.w, acc[grp*4+3][0]);
          acc[grp*4+3][1] = dot2(xb0, w4.x, acc[grp*4+3][1]);
          acc[grp*4+3][1] = dot2(xb1, w4.y, acc[grp*4+3][1]);
          acc[grp*4+3][1] = dot2(xb2, w4.z, acc[grp*4+3][1]);
          acc[grp*4+3][1] = dot2(xb3, w4.w, acc[grp*4+3][1]);
        }
      }
    }
  }

  // epilogue: theta direct, phi/g with 2x2 maxpool
#pragma unroll
  for (int grp = 0; grp < 6; ++grp) {
#pragma unroll
    for (int k = 0; k < 4; ++k) {
      const int r = rbase + grp * 4 + k;
      float a0 = acc[grp*4+k][0], a1 = acc[grp*4+k][1];
      if (r < 64) {
        theta[((size_t)(b * DD + r)) * NPIX + n0 + lane]      = f2b(a0);
        theta[((size_t)(b * DD + r)) * NPIX + n0 + 64 + lane] = f2b(a1);
      } else {
        float pm = fmaxf(a0, a1);                 // max over 2 spatial rows
        float po = fmaxf(pm, __shfl_xor(pm, 1));  // max over col pair
        if (!(lane & 1)) {
          int m = yp * 32 + (lane >> 1);
          if (r < 128) phi_t[((size_t)(b * MM + m)) * DD + (r - 64)] = f2b(po);
          else         g[((size_t)(b * VV + (r - 128))) * MM + m]    = f2b(po);
        }
      }
    }
  }
}

// ---------------------------------------------------------------------------
// K2: fused attention + output projection + residual, per 16-query tile.
// grid = 16 b * 256 qtiles.  Output write is dtype-adaptive (fp32 vs bf16).
// ---------------------------------------------------------------------------
__global__ __launch_bounds__(256) void k_attn(
    const u16* __restrict__ theta, const u16* __restrict__ phi_t,
    const u16* __restrict__ g, const u16* __restrict__ wo,
    const void* __restrict__ x, const float* __restrict__ gamma_p,
    const u32* __restrict__ meta, void* __restrict__ out)
{
  __shared__ __align__(16) u32 qs_u[16][36];   // packed d-pairs of Q tile
  __shared__ __align__(16) u32 sc[16][516];    // fp16 scores -> exp'd bf16 pairs
  union St {
    u16 phi[128][66];    // pass1: phi chunk [m][d]
    u32 g[256][20];      // pass3: g chunk [v][16 m-pairs]
    u16 ot[16][264];     // output phase: o tile [q][v]
  };
  __shared__ __align__(16) St st;
  __shared__ float pmax[16][16];
  __shared__ float psum[16][16];

  const int tid = threadIdx.x;
  const int blk = blockIdx.x;
  const int b  = blk >> 8;
  const int qt = blk & 255;
  const int nq = qt * 16;
  const int flag = (int)meta[0];

  // load Q tile as packed d-pairs
  for (int idx = tid; idx < 512; idx += 256) {
    int q = idx & 15, dp = idx >> 4;
    size_t base = ((size_t)(b * DD + 2 * dp)) * NPIX + nq + q;
    u32 lo = theta[base], hi = theta[base + NPIX];
    qs_u[q][dp] = lo | (hi << 16);
  }

  // ---- pass 1: raw scores, stored unpacked fp16 (one owner per element) ----
  {
    const int j  = tid & 127;
    const int qh = tid >> 7;
    for (int ch = 0; ch < 8; ++ch) {
      __syncthreads();
#pragma unroll 8
      for (int it = 0; it < 32; ++it) {
        int idx = tid + it * 256;
        int jm = idx >> 6, d = idx & 63;
        st.phi[jm][d] = phi_t[((size_t)(b * MM + ch * 128 + jm)) * DD + d];
      }
      __syncthreads();
      float accq[8];
#pragma unroll
      for (int q = 0; q < 8; ++q) accq[q] = 0.f;
#pragma unroll
      for (int dp4 = 0; dp4 < 8; ++dp4) {
        u32 u0 = *(const u32a*)&st.phi[j][dp4 * 8];
        u32 u1 = *(const u32a*)&st.phi[j][dp4 * 8 + 2];
        u32 u2 = *(const u32a*)&st.phi[j][dp4 * 8 + 4];
        u32 u3 = *(const u32a*)&st.phi[j][dp4 * 8 + 6];
#pragma unroll
        for (int q = 0; q < 8; ++q) {
          uint4 qv = *(const uint4a*)&qs_u[qh * 8 + q][dp4 * 4];
          accq[q] = dot2(u0, qv.x, accq[q]);
          accq[q] = dot2(u1, qv.y, accq[q]);
          accq[q] = dot2(u2, qv.z, accq[q]);
          accq[q] = dot2(u3, qv.w, accq[q]);
        }
      }
#pragma unroll
      for (int q = 0; q < 8; ++q) {
        float s = fminf(fmaxf(accq[q], -6.0e4f), 6.0e4f);  // fp16-safe clamp
        ((u16a*)&sc[qh * 8 + q][0])[ch * 128 + j] = f2h(s);
      }
    }
  }
  __syncthreads();

  // ---- pass 2: max, exp, sum; in-place repack to bf16 pairs ----
  const int q  = tid & 15;
  const int sg = tid >> 4;
  float si;
  {
    const u16a* scr = (const u16a*)&sc[q][0];
    float mx = -3.0e38f;
#pragma unroll 8
    for (int k = 0; k < 64; ++k) mx = fmaxf(mx, h2f(scr[sg * 64 + k]));
    pmax[q][sg] = mx;
    __syncthreads();
    float maxq = -3.0e38f;
#pragma unroll
    for (int i = 0; i < 16; ++i) maxq = fmaxf(maxq, pmax[q][i]);
    float s = 0.f;
#pragma unroll 4
    for (int kp = 0; kp < 32; ++kp) {
      int mp = sg * 32 + kp;
      u32 raw = sc[q][mp];
      float f0 = h2f((u16)(raw & 0xffffu));
      float f1 = h2f((u16)(raw >> 16));
      float e0 = __expf(fminf(f0 - maxq, 0.f));
      float e1 = __expf(fminf(f1 - maxq, 0.f));
      s += e0 + e1;
      sc[q][mp] = (u32)f2b(e0) | ((u32)f2b(e1) << 16);
    }
    psum[q][sg] = s;
    __syncthreads();
    float tot = 0.f;
#pragma unroll
    for (int i = 0; i < 16; ++i) tot += psum[q][i];
    si = 1.f / tot;
  }

  // ---- pass 3: o[v][q] = sum_m g[v][m] * beta[q][m] ----
  float acc3[16];
#pragma unroll
  for (int i = 0; i < 16; ++i) acc3[i] = 0.f;
  for (int ch = 0; ch < 32; ++ch) {
    __syncthreads();
    {
      const u16* gp = g + ((size_t)(b * VV + tid)) * MM + ch * 32;
      uint4 g0 = *(const uint4a*)(gp);
      uint4 g1 = *(const uint4a*)(gp + 8);
      uint4 g2 = *(const uint4a*)(gp + 16);
      uint4 g3 = *(const uint4a*)(gp + 24);
      *(uint4a*)&st.g[tid][0]  = g0;
      *(uint4a*)&st.g[tid][4]  = g1;
      *(uint4a*)&st.g[tid][8]  = g2;
      *(uint4a*)&st.g[tid][12] = g3;
    }
    __syncthreads();
    uint4 bq[4];
#pragma unroll
    for (int s = 0; s < 4; ++s) bq[s] = *(const uint4a*)&sc[q][ch * 16 + s * 4];
#pragma unroll
    for (int i = 0; i < 16; ++i) {
      const int v = sg + 16 * i;
#pragma unroll
      for (int s = 0; s < 4; ++s) {
        uint4 gq = *(const uint4a*)&st.g[v][4 * s];
        acc3[i] = dot2(gq.x, bq[s].x, acc3[i]);
        acc3[i] = dot2(gq.y, bq[s].y, acc3[i]);
        acc3[i] = dot2(gq.z, bq[s].z, acc3[i]);
        acc3[i] = dot2(gq.w, bq[s].w, acc3[i]);
      }
    }
  }

  // ---- o tile -> LDS (bf16), then fused w_o projection + residual ----
  __syncthreads();
#pragma unroll
  for (int i = 0; i < 16; ++i)
    ((u16a*)&st.ot[q][0])[sg + 16 * i] = f2b(acc3[i] * si);
  __syncthreads();

  {
    const float gmv = gamma_p[0];
    for (int k = 0; k < 32; ++k) {
      const int oc = sg * 32 + k;
      const u32a* wr = (const u32a*)(wo + (size_t)oc * VV);
      float a = 0.f;
#pragma unroll 8
      for (int w = 0; w < 32; ++w) {
        uint4 w4 = *(const uint4a*)(wr + 4 * w);
        uint4 o4 = *(const uint4a*)&st.ot[q][8 * w];
        a = dot2(w4.x, o4.x, a);
        a = dot2(w4.y, o4.y, a);
        a = dot2(w4.z, o4.z, a);
        a = dot2(w4.w, o4.w, a);
      }
      size_t off = ((size_t)(b * CIN + oc)) * NPIX + nq + q;
      if (flag) {
        float xv = ((const f32a*)x)[off];
        ((f32a*)out)[off] = gmv * a + xv;          // fp32 world: exact residual
      } else {
        float xv = b2f(((const u16a*)x)[off]);
        ((u16a*)out)[off] = f2b(gmv * a + xv);     // bf16 world
      }
    }
  }
}

extern "C" void kernel_launch(void* const* d_in, const int* in_sizes, int n_in,
                              void* d_out, int out_size, void* d_ws, size_t ws_size,
                              hipStream_t stream) {
  (void)in_sizes; (void)n_in; (void)out_size; (void)ws_size;
  const void* x  = d_in[0];
  const void* wt = d_in[1];
  const void* wp = d_in[2];
  const void* wg = d_in[3];
  const void* wo = d_in[4];
  const void* gm = d_in[5];

  u16* theta = (u16*)d_ws;                              // [16][64][4096]  bf16
  u16* phi_t = theta + (size_t)BATCH * DD * NPIX;       // [16][1024][64]  bf16 (transposed)
  u16* g     = phi_t + (size_t)BATCH * MM * DD;         // [16][256][1024] bf16
  u16* wbf   = g     + (size_t)BATCH * VV * MM;         // 327680 bf16 weights
  float* gamma_f = (float*)(wbf + 327680);              // converted gamma
  u32* meta      = (u32*)(gamma_f + 1);                 // dtype flag

  hipLaunchKernelGGL(k_detect, dim3(1), dim3(256), 0, stream, x, meta);
  hipLaunchKernelGGL(k_cvt, dim3(1280), dim3(256), 0, stream,
                     wt, wp, wg, wo, gm, meta, wbf, gamma_f);
  hipLaunchKernelGGL(k_proj, dim3(BATCH * 32 * 4), dim3(256), 0, stream,
                     x, wbf, wbf + 32768, wbf + 65536, meta, theta, phi_t, g);
  hipLaunchKernelGGL(k_attn, dim3(BATCH * 256), dim3(256), 0, stream,
                     theta, phi_t, g, wbf + 196608, x, gamma_f, meta, d_out);
}